// Round 15
// baseline (77.415 us; speedup 1.0000x reference)
//
#include <hip/hip_runtime.h>
#include <hip/hip_bf16.h>
#include <math.h>

// Trittention forward: B=2,H=8,S=192,D=64, fp32 in/out.
// scores[q,t,s] = sum_h q[h]*k1[t,h]*k2[s,h]  ==  (W @ k2^T), W = q (.) k1
// softmax over flat (t,s); z = (sum_t At v1 + sum_s As v2)/suma via marginals.
// Round 15: t-split. Block = 1q x 96t x 192s (grid 6144). All outputs are
// additive in t: block writes partial numerator (64f) + partial suma to a
// DISJOINT ws slot (deterministic, no cross-block atomics); finish kernel
// combines. Per-thread work 4x smaller than r14 (36 exp, 18 MFMA); j-outer
// single-acc restructure + 1q staging cuts live regs (target <=64 total ->
// 8 waves/SIMD tier); LDS 38.7KB -> 4 blocks/CU by LDS.
// Spill sentinel: WRITE_SIZE >> 20MB.

#define SS 192
#define TH 96     // t-half per block
#define DD 64
#define NT 512    // 8 waves: 2 (t) x 4 (s), wave tile 48x48

typedef __attribute__((ext_vector_type(8))) short bf16x8;
typedef __attribute__((ext_vector_type(4))) float f32x4;

static __device__ __forceinline__ unsigned pk_bf16(float a, float b) {
    union { __hip_bfloat162 h; unsigned u; } cv;
    cv.h = __float22bfloat162_rn(float2{a, b});   // v_cvt_pk_bf16_f32 (RNE)
    return cv.u;
}

// one DPP-add step: v += v[lane ^pattern], within rows of 16 lanes
#define DPP_STEP(v, CTRL)                                                   \
    (v) += __int_as_float(__builtin_amdgcn_update_dpp(                      \
        0, __float_as_int(v), (CTRL), 0xF, 0xF, true))

static __device__ __forceinline__ float row16_sum(float v) {
    DPP_STEP(v, 0xB1);   // quad_perm [1,0,3,2]  : xor 1
    DPP_STEP(v, 0x4E);   // quad_perm [2,3,0,1]  : xor 2
    DPP_STEP(v, 0x141);  // row_half_mirror
    DPP_STEP(v, 0x140);  // row_mirror
    return v;            // all 16 lanes of the row hold the row sum
}

// ---- prepack: k2 fp32 -> bf16, stored PRE-SWIZZLED (chunk c at c^(r&7)) ----
__global__ __launch_bounds__(256) void k2_pack(const float* __restrict__ k2g,
                                               uint4* __restrict__ outp) {
    int i = blockIdx.x * 256 + threadIdx.x;   // 16B-chunk id, 0..24575
    const float4* in = (const float4*)k2g;
    float4 a = in[2 * i], b = in[2 * i + 1];
    uint4 w;
    w.x = pk_bf16(a.x, a.y);
    w.y = pk_bf16(a.z, a.w);
    w.z = pk_bf16(b.x, b.y);
    w.w = pk_bf16(b.z, b.w);
    int ih = i & 1535;                        // within-head chunk
    int r = ih >> 3, c = ih & 7;
    outp[(i & ~1535) | (r * 8 + (c ^ (r & 7)))] = w;
}

// red layout: At[0..96) | As[96..288) | zsh[288..352)
__launch_bounds__(NT, 4)
__global__ void tritt_half(const float* __restrict__ qg,
                           const float* __restrict__ k1g,
                           const uint4* __restrict__ k2p,  // bf16, pre-swizzled
                           const float* __restrict__ v1g,
                           const float* __restrict__ v2g,
                           float* __restrict__ partial) {  // [nq][2][72]
    __shared__ uint4 k2l[SS * 8];              // 24.5 KB
    __shared__ uint4 wl[TH * 8];               // 12.25 KB
    __shared__ float red[TH + SS + DD];        // 352 floats

    const int tid = threadIdx.x;
    const int bid = blockIdx.x;
    const int q   = bid >> 1;             // global q row
    const int th  = bid & 1;              // t-half (0: rows 0..95, 1: 96..191)
    const int head = q / SS;
    const size_t hb = (size_t)head * SS * DD;

    // k2 staging: direct global->LDS DMA (source pre-swizzled, dest linear)
    const uint4* k2h = k2p + (size_t)head * (SS * 8);
    #pragma unroll
    for (int it = 0; it < (SS * 8) / NT; ++it) {   // 3 iters
        int f8 = tid + it * NT;
        __builtin_amdgcn_global_load_lds(
            (const __attribute__((address_space(1))) unsigned int*)(k2h + f8),
            (__attribute__((address_space(3))) unsigned int*)&k2l[f8],
            16, 0, 0);
    }

    if (tid < TH + SS + DD) red[tid] = 0.f;

    // ---- stage W = q*k1*log2e for this t-half (96 rows) ----
    const float L2E = 1.44269504088896340736f;
    const float4* k1v = (const float4*)(k1g + hb);
    const float4* qv  = (const float4*)(qg + (size_t)q * DD);
    {
        const int c = tid & 7;            // chunk col: constant per thread
        float4 p0 = qv[2 * c], p1 = qv[2 * c + 1];
        p0.x *= L2E; p0.y *= L2E; p0.z *= L2E; p0.w *= L2E;
        p1.x *= L2E; p1.y *= L2E; p1.z *= L2E; p1.w *= L2E;
        #pragma unroll 1
        for (int it = 0; it < 2; ++it) {   // 768 chunks over 512 threads
            int f8 = tid + it * NT;
            if (f8 < TH * 8) {
                int r = f8 >> 3;           // local row
                int gt = th * TH + r;      // global t
                float4 a0 = k1v[gt * 16 + 2 * c];
                float4 a1 = k1v[gt * 16 + 2 * c + 1];
                uint4 w;
                w.x = pk_bf16(a0.x * p0.x, a0.y * p0.y);
                w.y = pk_bf16(a0.z * p0.z, a0.w * p0.w);
                w.z = pk_bf16(a1.x * p1.x, a1.y * p1.y);
                w.w = pk_bf16(a1.z * p1.z, a1.w * p1.w);
                wl[r * 8 + (c ^ (r & 7))] = w;
            }
        }
    }
    __syncthreads();

    // ---- fused score-GEMM + exp + marginals. Wave (wt,ws4) owns 48x48. ----
    const int lane = tid & 63;
    const int wid  = tid >> 6;
    const int wt   = wid >> 2;            // 0..1 (t quarter: 48 rows)
    const int ws4  = wid & 3;             // 0..3 (s quarter: 48 cols)
    const int lrow = lane & 15;
    const int lk   = lane >> 4;           // 0..3 (k-group)
    const int lrm  = lrow & 7;
    const int sw0 = lk ^ lrm;             // ks = 0 swizzled chunk
    const int sw1 = (4 + lk) ^ lrm;       // ks = 1
    const int ab  = (wt * 48 + lrow) * 8; // A chunk base (48 ≡ 0 mod 8)
    const int bb  = (ws4 * 48 + lrow) * 8;

    float colp[3] = {0.f, 0.f, 0.f};
    #pragma unroll
    for (int i = 0; i < 3; ++i) {
        bf16x8 afr0 = *(const bf16x8*)&wl[ab + i * 128 + sw0];
        bf16x8 afr1 = *(const bf16x8*)&wl[ab + i * 128 + sw1];
        float rs[4] = {0.f, 0.f, 0.f, 0.f};
        #pragma unroll
        for (int j = 0; j < 3; ++j) {
            f32x4 acc = (f32x4){0.f, 0.f, 0.f, 0.f};
            bf16x8 b0 = *(const bf16x8*)&k2l[bb + j * 128 + sw0];
            acc = __builtin_amdgcn_mfma_f32_16x16x32_bf16(afr0, b0, acc, 0, 0, 0);
            bf16x8 b1 = *(const bf16x8*)&k2l[bb + j * 128 + sw1];
            acc = __builtin_amdgcn_mfma_f32_16x16x32_bf16(afr1, b1, acc, 0, 0, 0);
            // D mapping: col(s) = lane&15, row(t) = (lane>>4)*4 + reg.
            #pragma unroll
            for (int r = 0; r < 4; ++r) {
                float p = __builtin_amdgcn_exp2f(acc[r]);   // = exp(score)
                rs[r] += p;
                colp[j] += p;
            }
        }
        #pragma unroll
        for (int r = 0; r < 4; ++r) {
            float v = row16_sum(rs[r]);   // DPP, all-VALU
            if (lrow == 0)
                atomicAdd(&red[wt * 48 + i * 16 + lk * 4 + r], v);   // At
        }
    }
    #pragma unroll
    for (int j = 0; j < 3; ++j) {
        float v = colp[j];
        v += __shfl_xor(v, 16, 64);
        v += __shfl_xor(v, 32, 64);
        if (lane < 16)
            atomicAdd(&red[TH + ws4 * 48 + j * 16 + lane], v);       // As
    }
    __syncthreads();

    // ---- partial suma = sum(At) (wave 0 only) ----
    float suma = 0.f;
    if (wid == 0) {
        float s = red[lane] + ((lane < 32) ? red[64 + lane] : 0.f);
        #pragma unroll
        for (int off = 1; off < 64; off <<= 1)
            s += __shfl_xor(s, off, 64);
        suma = s;
    }

    // ---- partial numerator: At(local t) @ v1 + As(partial) @ v2 ----
    const int d = lane;
    const int g = wid;                    // 0..7
    const float* v1p = v1g + hb;
    const float* v2p = v2g + hb;
    float zp = 0.f;
    #pragma unroll 4
    for (int r = 0; r < 12; ++r) {        // 12 v1 rows per wave
        int tl = g * 12 + r;
        zp = fmaf(red[tl], v1p[(size_t)(th * TH + tl) * DD + d], zp);
    }
    #pragma unroll 4
    for (int r = 0; r < 24; ++r) {        // 24 v2 rows per wave
        int s = g * 24 + r;
        zp = fmaf(red[TH + s], v2p[(size_t)s * DD + d], zp);
    }
    atomicAdd(&red[TH + SS + d], zp);
    __syncthreads();

    float* slot = partial + ((size_t)q * 2 + th) * 72;
    if (tid < DD) slot[tid] = red[TH + SS + tid];
    if (tid == 0) slot[64] = suma;
}

// ---- finish: z = (n0+n1)/(s0+s1); lse = log(s0+s1) ----
__global__ __launch_bounds__(256) void tritt_fin(const float* __restrict__ partial,
                                                 float* __restrict__ zg,
                                                 float* __restrict__ lseg) {
    int idx = blockIdx.x * 256 + threadIdx.x;   // nq*64 total
    int q = idx >> 6, d = idx & 63;
    const float* s0 = partial + (size_t)q * 144;
    const float* s1 = s0 + 72;
    float suma = s0[64] + s1[64];
    zg[(size_t)q * DD + d] = (s0[d] + s1[d]) / suma;
    if (d == 0) lseg[q] = logf(suma);
}

extern "C" void kernel_launch(void* const* d_in, const int* in_sizes, int n_in,
                              void* d_out, int out_size, void* d_ws, size_t ws_size,
                              hipStream_t stream) {
    const float* q  = (const float*)d_in[0];
    const float* k1 = (const float*)d_in[1];
    const float* k2 = (const float*)d_in[2];
    const float* v1 = (const float*)d_in[3];
    const float* v2 = (const float*)d_in[4];
    float* out = (float*)d_out;

    const int nq = in_sizes[0] / DD;      // B*H*S = 3072
    const int nheads = nq / SS;           // 16
    float* zout   = out;
    float* lseout = out + (size_t)nq * DD;

    uint4* k2pack  = (uint4*)d_ws;                          // 384 KiB
    float* partial = (float*)((char*)d_ws + (size_t)nheads * SS * 8 * 16);
    // partial: nq*2*72 floats = 1.77 MB (disjoint per (q,half), overwritten
    // in full each call -> deterministic)

    // prepack k2 -> bf16 pre-swizzled (q-invariant; deterministic each call)
    int n8 = nheads * SS * DD / 8;        // 24576
    hipLaunchKernelGGL(k2_pack, dim3(n8 / 256), dim3(256), 0, stream, k2, k2pack);

    hipLaunchKernelGGL(tritt_half, dim3(nq * 2), dim3(NT), 0, stream,
                       q, k1, (const uint4*)k2pack, v1, v2, partial);

    hipLaunchKernelGGL(tritt_fin, dim3(nq * DD / 256), dim3(256), 0, stream,
                       partial, zout, lseout);
}

// Round 16
// 59.092 us; speedup vs baseline: 1.3101x; 1.3101x over previous
//
#include <hip/hip_runtime.h>
#include <hip/hip_bf16.h>
#include <math.h>

// Trittention forward: B=2,H=8,S=192,D=64, fp32 in/out.
// scores[q,t,s] = sum_h q[h]*k1[t,h]*k2[s,h]  ==  (W @ k2^T), W = q (.) k1
// softmax over flat (t,s); z = (sum_t At v1 + sum_s As v2)/suma via marginals.
// Round 16: round-8 geometry (1 q/block, grid 3072, full 192x192) +
// round-15's register-lean inner loop (j-outer, single f32x4 acc, afr pair
// per i, b-fragments re-read per j). r15 proved this shape allocates ~36
// VGPR -> 8-waves/SIMD tier; LDS 51KB -> 3 blocks/CU (24 waves, 75%) vs
// r8's 2 blocks (38%). Same math order as r8 -> absmax identical.
// Spill sentinel: WRITE_SIZE.

#define SS 192
#define DD 64
#define NT 512   // 8 waves: 2 (t) x 4 (s) wave grid, wave tile 96x48

typedef __attribute__((ext_vector_type(8))) short bf16x8;
typedef __attribute__((ext_vector_type(4))) float f32x4;

static __device__ __forceinline__ unsigned pk_bf16(float a, float b) {
    union { __hip_bfloat162 h; unsigned u; } cv;
    cv.h = __float22bfloat162_rn(float2{a, b});   // v_cvt_pk_bf16_f32 (RNE)
    return cv.u;
}

// one DPP-add step: v += v[lane ^pattern], within rows of 16 lanes
#define DPP_STEP(v, CTRL)                                                   \
    (v) += __int_as_float(__builtin_amdgcn_update_dpp(                      \
        0, __float_as_int(v), (CTRL), 0xF, 0xF, true))

static __device__ __forceinline__ float row16_sum(float v) {
    DPP_STEP(v, 0xB1);   // quad_perm [1,0,3,2]  : xor 1
    DPP_STEP(v, 0x4E);   // quad_perm [2,3,0,1]  : xor 2
    DPP_STEP(v, 0x141);  // row_half_mirror
    DPP_STEP(v, 0x140);  // row_mirror
    return v;            // all 16 lanes of the row hold the row sum
}

// ---- prepack: k2 fp32 -> bf16, stored PRE-SWIZZLED (chunk c at c^(r&7)) ----
__global__ __launch_bounds__(256) void k2_pack(const float* __restrict__ k2g,
                                               uint4* __restrict__ outp) {
    int i = blockIdx.x * 256 + threadIdx.x;   // 16B-chunk id, 0..24575
    const float4* in = (const float4*)k2g;
    float4 a = in[2 * i], b = in[2 * i + 1];
    uint4 w;
    w.x = pk_bf16(a.x, a.y);
    w.y = pk_bf16(a.z, a.w);
    w.z = pk_bf16(b.x, b.y);
    w.w = pk_bf16(b.z, b.w);
    int ih = i & 1535;                        // within-head chunk
    int r = ih >> 3, c = ih & 7;
    outp[(i & ~1535) | (r * 8 + (c ^ (r & 7)))] = w;
}

__launch_bounds__(NT, 4)
__global__ void tritt_fwd(const float* __restrict__ qg,
                          const float* __restrict__ k1g,
                          const uint4* __restrict__ k2p,   // bf16, pre-swizzled
                          const float* __restrict__ v1g,
                          const float* __restrict__ v2g,
                          float* __restrict__ zg,
                          float* __restrict__ lseg) {
    // bf16 tiles, row = 64 bf16 = 8 chunks of 16B; chunk c stored at c^(r&7).
    __shared__ uint4 k2l[SS * 8];              // 24.5 KB
    __shared__ uint4 wl[SS * 8];               // 24.5 KB
    __shared__ float At[SS];
    __shared__ float As[SS];
    __shared__ float zsh[DD];

    const int tid = threadIdx.x;
    const int bid = blockIdx.x;           // (b*H + n)*S + q
    const int head = bid / SS;
    const size_t hb = (size_t)head * SS * DD;

    // k2 staging: direct global->LDS DMA (source pre-swizzled, dest linear)
    const uint4* k2h = k2p + (size_t)head * (SS * 8);
    #pragma unroll
    for (int it = 0; it < (SS * 8) / NT; ++it) {   // 3 iters
        int f8 = tid + it * NT;
        __builtin_amdgcn_global_load_lds(
            (const __attribute__((address_space(1))) unsigned int*)(k2h + f8),
            (__attribute__((address_space(3))) unsigned int*)&k2l[f8],
            16, 0, 0);
    }

    if (tid < SS) At[tid] = 0.f;
    else if (tid < 2 * SS) As[tid - SS] = 0.f;
    else if (tid < 2 * SS + DD) zsh[tid - 2 * SS] = 0.f;

    // ---- stage W = q*k1*log2e into LDS as bf16 (swizzled) ----
    const float L2E = 1.44269504088896340736f;
    const float4* k1v = (const float4*)(k1g + hb);
    const float4* qv  = (const float4*)(qg + (size_t)bid * DD);
    {
        const int c = tid & 7;            // chunk within row: constant/thread
        float4 q0 = qv[2 * c], q1 = qv[2 * c + 1];
        q0.x *= L2E; q0.y *= L2E; q0.z *= L2E; q0.w *= L2E;
        q1.x *= L2E; q1.y *= L2E; q1.z *= L2E; q1.w *= L2E;
        #pragma unroll
        for (int it = 0; it < (SS * 8) / NT; ++it) {   // 3 iters
            int f8 = tid + it * NT;        // 16B-chunk id
            int r = f8 >> 3;
            float4 a0 = k1v[2 * f8], a1 = k1v[2 * f8 + 1];
            uint4 w;
            w.x = pk_bf16(a0.x * q0.x, a0.y * q0.y);
            w.y = pk_bf16(a0.z * q0.z, a0.w * q0.w);
            w.z = pk_bf16(a1.x * q1.x, a1.y * q1.y);
            w.w = pk_bf16(a1.z * q1.z, a1.w * q1.w);
            wl[r * 8 + (c ^ (r & 7))] = w;
        }
    }
    __syncthreads();

    // ---- fused score-GEMM + exp + marginals. Wave (wt,ws) owns 96x48. ----
    const int lane = tid & 63;
    const int wid  = tid >> 6;
    const int wt   = wid >> 2;            // 0..1
    const int ws   = wid & 3;             // 0..3
    const int lrow = lane & 15;
    const int lk   = lane >> 4;           // 0..3 (k-group)
    const int lrm  = lrow & 7;

    // Swizzle term (ks*4+lk)^lrm is i/j-independent (96,48,16 all ≡0 mod 8).
    const int sw0 = lk ^ lrm;             // ks = 0
    const int sw1 = (4 + lk) ^ lrm;       // ks = 1
    const int ab  = (wt * 96 + lrow) * 8; // A chunk base
    const int bb  = (ws * 48 + lrow) * 8; // B chunk base

    float colp[3] = {0.f, 0.f, 0.f};
    #pragma unroll
    for (int i = 0; i < 6; ++i) {
        bf16x8 afr0 = *(const bf16x8*)&wl[ab + i * 128 + sw0];
        bf16x8 afr1 = *(const bf16x8*)&wl[ab + i * 128 + sw1];
        float rs[4] = {0.f, 0.f, 0.f, 0.f};
        #pragma unroll
        for (int j = 0; j < 3; ++j) {
            f32x4 acc = (f32x4){0.f, 0.f, 0.f, 0.f};
            bf16x8 b0 = *(const bf16x8*)&k2l[bb + j * 128 + sw0];
            acc = __builtin_amdgcn_mfma_f32_16x16x32_bf16(afr0, b0, acc, 0, 0, 0);
            bf16x8 b1 = *(const bf16x8*)&k2l[bb + j * 128 + sw1];
            acc = __builtin_amdgcn_mfma_f32_16x16x32_bf16(afr1, b1, acc, 0, 0, 0);
            // D mapping: col(s) = lane&15, row(t) = (lane>>4)*4 + reg.
            #pragma unroll
            for (int r = 0; r < 4; ++r) {
                float p = __builtin_amdgcn_exp2f(acc[r]);   // = exp(score)
                rs[r] += p;
                colp[j] += p;
            }
        }
        #pragma unroll
        for (int r = 0; r < 4; ++r) {
            float v = row16_sum(rs[r]);   // DPP, all-VALU
            if (lrow == 0)
                atomicAdd(&At[wt * 96 + i * 16 + lk * 4 + r], v);
        }
    }
    #pragma unroll
    for (int j = 0; j < 3; ++j) {
        float v = colp[j];
        v += __shfl_xor(v, 16, 64);
        v += __shfl_xor(v, 32, 64);
        if (lane < 16)
            atomicAdd(&As[ws * 48 + j * 16 + lane], v);
    }
    __syncthreads();

    // ---- suma (redundant per-wave reduce; no extra barrier) ----
    float suma = At[lane] + At[lane + 64] + At[lane + 128];
    suma = row16_sum(suma);
    suma += __shfl_xor(suma, 16, 64);
    suma += __shfl_xor(suma, 32, 64);

    // ---- epilogue: z[d] = (sum_t At v1 + sum_s As v2) / suma ----
    const int d = tid & 63;
    const int g = tid >> 6;               // 0..7, each covers 24 rows
    const float* v1p = v1g + hb;
    const float* v2p = v2g + hb;
    float zp = 0.f;
    #pragma unroll 4
    for (int r = 0; r < 24; ++r) {
        int t = g * 24 + r;
        zp = fmaf(At[t], v1p[t * DD + d], zp);
        zp = fmaf(As[t], v2p[t * DD + d], zp);
    }
    atomicAdd(&zsh[d], zp);
    __syncthreads();

    if (tid < DD) zg[(size_t)bid * DD + tid] = zsh[tid] / suma;
    if (tid == 0) lseg[bid] = logf(suma);
}

extern "C" void kernel_launch(void* const* d_in, const int* in_sizes, int n_in,
                              void* d_out, int out_size, void* d_ws, size_t ws_size,
                              hipStream_t stream) {
    const float* q  = (const float*)d_in[0];
    const float* k1 = (const float*)d_in[1];
    const float* k2 = (const float*)d_in[2];
    const float* v1 = (const float*)d_in[3];
    const float* v2 = (const float*)d_in[4];
    float* out = (float*)d_out;

    const int nq = in_sizes[0] / DD;      // B*H*S = 3072
    const int nheads = nq / SS;           // 16
    float* zout   = out;
    float* lseout = out + (size_t)nq * DD;
    uint4* k2pack = (uint4*)d_ws;         // nheads*192*64 bf16 = 384 KiB

    // prepack k2 -> bf16 pre-swizzled (q-invariant; deterministic each call)
    int n8 = nheads * SS * DD / 8;        // 24576
    hipLaunchKernelGGL(k2_pack, dim3(n8 / 256), dim3(256), 0, stream, k2, k2pack);

    dim3 grid(nq), block(NT);
    hipLaunchKernelGGL(tritt_fwd, grid, block, 0, stream,
                       q, k1, (const uint4*)k2pack, v1, v2, zout, lseout);
}

// Round 17
// 52.698 us; speedup vs baseline: 1.4690x; 1.1213x over previous
//
#include <hip/hip_runtime.h>
#include <hip/hip_bf16.h>
#include <math.h>

// Trittention forward: B=2,H=8,S=192,D=64, fp32 in/out.
// scores[q,t,s] = sum_h q[h]*k1[t,h]*k2[s,h]  ==  (W @ k2^T), W = q (.) k1
// softmax over flat (t,s); z = (sum_t At v1 + sum_s As v2)/suma via marginals.
// Round 17: r14 base (best, 53.4us; 2q/block, hoisted bfr, prepacked k2,
// DPP reduce) + dep-chain cuts in the exp phase:
//  - rs[4]/colp[3] scalar accumulators -> f32x4 vector accumulators
//    (rsv += pv, cv[j] += pv): breaks the 72-deep serial colp chain into
//    4 independent lanes, enables v_pk_add_f32, halves add issue;
//    colp horizontal-summed once at loop exit.
//  - k2_pack at 512 threads (less helper-kernel tail).
// Occupancy pinned at 2 blocks/CU for this family (r9/r15/r16 evidence);
// this round attacks per-wave latency only. Spill sentinel: WRITE_SIZE.

#define SS 192
#define DD 64
#define NT 512   // 8 waves: 2 (t) x 4 (s) wave grid, wave tile 96x48

typedef __attribute__((ext_vector_type(8))) short bf16x8;
typedef __attribute__((ext_vector_type(4))) float f32x4;

static __device__ __forceinline__ unsigned pk_bf16(float a, float b) {
    union { __hip_bfloat162 h; unsigned u; } cv;
    cv.h = __float22bfloat162_rn(float2{a, b});   // v_cvt_pk_bf16_f32 (RNE)
    return cv.u;
}

// one DPP-add step: v += v[lane ^pattern], within rows of 16 lanes
#define DPP_STEP(v, CTRL)                                                   \
    (v) += __int_as_float(__builtin_amdgcn_update_dpp(                      \
        0, __float_as_int(v), (CTRL), 0xF, 0xF, true))

static __device__ __forceinline__ float row16_sum(float v) {
    DPP_STEP(v, 0xB1);   // quad_perm [1,0,3,2]  : xor 1
    DPP_STEP(v, 0x4E);   // quad_perm [2,3,0,1]  : xor 2
    DPP_STEP(v, 0x141);  // row_half_mirror
    DPP_STEP(v, 0x140);  // row_mirror
    return v;            // all 16 lanes of the row hold the row sum
}

// ---- prepack: k2 fp32 -> bf16, stored PRE-SWIZZLED (chunk c at c^(r&7)) ----
__global__ __launch_bounds__(512) void k2_pack(const float* __restrict__ k2g,
                                               uint4* __restrict__ outp) {
    int i = blockIdx.x * 512 + threadIdx.x;   // 16B-chunk id, 0..24575
    const float4* in = (const float4*)k2g;
    float4 a = in[2 * i], b = in[2 * i + 1];
    uint4 w;
    w.x = pk_bf16(a.x, a.y);
    w.y = pk_bf16(a.z, a.w);
    w.z = pk_bf16(b.x, b.y);
    w.w = pk_bf16(b.z, b.w);
    int ih = i & 1535;                        // within-head chunk
    int r = ih >> 3, c = ih & 7;
    outp[(i & ~1535) | (r * 8 + (c ^ (r & 7)))] = w;
}

#define AT(qq, t) red[(qq) * SS + (t)]
#define AS(qq, s) red[2 * SS + (qq) * SS + (s)]
#define ZSH(qq, d) red[4 * SS + (qq) * DD + (d)]

__launch_bounds__(NT, 4)
__global__ void tritt_fwd(const float* __restrict__ qg,
                          const float* __restrict__ k1g,
                          const uint4* __restrict__ k2p,   // bf16, pre-swizzled
                          const float* __restrict__ v1g,
                          const float* __restrict__ v2g,
                          float* __restrict__ zg,
                          float* __restrict__ lseg) {
    // bf16 tiles, row = 64 bf16 = 8 chunks of 16B; chunk c stored at c^(r&7).
    __shared__ uint4 k2l[SS * 8];
    __shared__ uint4 wl[2][SS * 8];
    __shared__ float red[4 * SS + 2 * DD];    // At[2],As[2],zsh[2]

    const int tid = threadIdx.x;
    const int q0 = 2 * blockIdx.x;        // global q row; q0,q0+1 same head
    const int head = q0 / SS;
    const size_t hb = (size_t)head * SS * DD;

    // k2 staging: direct global->LDS DMA (source pre-swizzled, dest linear)
    const uint4* k2h = k2p + (size_t)head * (SS * 8);
    #pragma unroll
    for (int it = 0; it < (SS * 8) / NT; ++it) {   // 3 iters
        int f8 = tid + it * NT;
        __builtin_amdgcn_global_load_lds(
            (const __attribute__((address_space(1))) unsigned int*)(k2h + f8),
            (__attribute__((address_space(3))) unsigned int*)&k2l[f8],
            16, 0, 0);
    }

    red[tid] = 0.f;
    if (tid < 4 * SS + 2 * DD - NT) red[tid + NT] = 0.f;

    // ---- stage W_q = q*k1*log2e for both q's (k1 loaded once) ----
    const float L2E = 1.44269504088896340736f;
    const float4* k1v = (const float4*)(k1g + hb);
    const float4* qv0 = (const float4*)(qg + (size_t)q0 * DD);
    {
        const int c = tid & 7;            // chunk within row: constant/thread
        float4 p00 = qv0[2 * c], p01 = qv0[2 * c + 1];
        float4 p10 = qv0[16 + 2 * c], p11 = qv0[16 + 2 * c + 1]; // q0+1 row
        p00.x *= L2E; p00.y *= L2E; p00.z *= L2E; p00.w *= L2E;
        p01.x *= L2E; p01.y *= L2E; p01.z *= L2E; p01.w *= L2E;
        p10.x *= L2E; p10.y *= L2E; p10.z *= L2E; p10.w *= L2E;
        p11.x *= L2E; p11.y *= L2E; p11.z *= L2E; p11.w *= L2E;
        #pragma unroll 1
        for (int it = 0; it < (SS * 8) / NT; ++it) {   // 3 serial iters
            int f8 = tid + it * NT;        // 16B-chunk id
            int r = f8 >> 3;
            int idx = r * 8 + (c ^ (r & 7));
            float4 a0 = k1v[2 * f8], a1 = k1v[2 * f8 + 1];
            uint4 w;
            w.x = pk_bf16(a0.x * p00.x, a0.y * p00.y);
            w.y = pk_bf16(a0.z * p00.z, a0.w * p00.w);
            w.z = pk_bf16(a1.x * p01.x, a1.y * p01.y);
            w.w = pk_bf16(a1.z * p01.z, a1.w * p01.w);
            wl[0][idx] = w;
            w.x = pk_bf16(a0.x * p10.x, a0.y * p10.y);
            w.y = pk_bf16(a0.z * p10.z, a0.w * p10.w);
            w.z = pk_bf16(a1.x * p11.x, a1.y * p11.y);
            w.w = pk_bf16(a1.z * p11.z, a1.w * p11.w);
            wl[1][idx] = w;
        }
    }
    __syncthreads();

    // ---- fused score-GEMM + exp + marginals. Wave (wt,ws) owns 96x48. ----
    const int lane = tid & 63;
    const int wid  = tid >> 6;
    const int wt   = wid >> 2;            // 0..1
    const int ws   = wid & 3;             // 0..3
    const int lrow = lane & 15;
    const int lk   = lane >> 4;           // 0..3 (k-group)
    const int lrm  = lrow & 7;

    // Swizzle term (ks*4+lk)^lrm is i/j-independent (96,48,16 all ≡0 mod 8).
    const int sw0 = lk ^ lrm;             // ks = 0
    const int sw1 = (4 + lk) ^ lrm;       // ks = 1
    const int ab  = (wt * 96 + lrow) * 8; // A chunk base
    const int bb  = (ws * 48 + lrow) * 8; // B chunk base

    // B-fragments hoisted ONCE for the whole block (k2 is q-invariant).
    bf16x8 bfr[2][3];
    #pragma unroll
    for (int j = 0; j < 3; ++j) {
        bfr[0][j] = *(const bf16x8*)&k2l[bb + j * 128 + sw0];
        bfr[1][j] = *(const bf16x8*)&k2l[bb + j * 128 + sw1];
    }

    #pragma unroll 1
    for (int qq = 0; qq < 2; ++qq) {
        const uint4* wlq = wl[qq];
        f32x4 cv[3];                      // per-column partials (vector)
        #pragma unroll
        for (int j = 0; j < 3; ++j) cv[j] = (f32x4){0.f, 0.f, 0.f, 0.f};
        #pragma unroll
        for (int i = 0; i < 6; ++i) {
            f32x4 acc[3];
            #pragma unroll
            for (int j = 0; j < 3; ++j) acc[j] = (f32x4){0.f, 0.f, 0.f, 0.f};
            {   // ks = 0
                bf16x8 afr = *(const bf16x8*)&wlq[ab + i * 128 + sw0];
                #pragma unroll
                for (int j = 0; j < 3; ++j)
                    acc[j] = __builtin_amdgcn_mfma_f32_16x16x32_bf16(
                        afr, bfr[0][j], acc[j], 0, 0, 0);
            }
            {   // ks = 1
                bf16x8 afr = *(const bf16x8*)&wlq[ab + i * 128 + sw1];
                #pragma unroll
                for (int j = 0; j < 3; ++j)
                    acc[j] = __builtin_amdgcn_mfma_f32_16x16x32_bf16(
                        afr, bfr[1][j], acc[j], 0, 0, 0);
            }
            // D mapping: col(s) = lane&15, row(t) = (lane>>4)*4 + reg.
            f32x4 rsv = (f32x4){0.f, 0.f, 0.f, 0.f};
            #pragma unroll
            for (int j = 0; j < 3; ++j) {
                f32x4 pv;
                #pragma unroll
                for (int r = 0; r < 4; ++r)
                    pv[r] = __builtin_amdgcn_exp2f(acc[j][r]);
                rsv += pv;                // 4 independent lanes (pk adds)
                cv[j] += pv;
            }
            #pragma unroll
            for (int r = 0; r < 4; ++r) {
                float v = row16_sum(rsv[r]);   // DPP, all-VALU
                if (lrow == 0)
                    atomicAdd(&AT(qq, wt * 96 + i * 16 + lk * 4 + r), v);
            }
        }
        #pragma unroll
        for (int j = 0; j < 3; ++j) {
            float v = (cv[j][0] + cv[j][1]) + (cv[j][2] + cv[j][3]);
            v += __shfl_xor(v, 16, 64);
            v += __shfl_xor(v, 32, 64);
            if (lane < 16)
                atomicAdd(&AS(qq, ws * 48 + j * 16 + lane), v);
        }
    }
    __syncthreads();

    // ---- sumas (redundant per-wave reduce; no extra barrier) ----
    float suma0 = AT(0, lane) + AT(0, lane + 64) + AT(0, lane + 128);
    suma0 = row16_sum(suma0);
    suma0 += __shfl_xor(suma0, 16, 64);
    suma0 += __shfl_xor(suma0, 32, 64);
    float suma1 = AT(1, lane) + AT(1, lane + 64) + AT(1, lane + 128);
    suma1 = row16_sum(suma1);
    suma1 += __shfl_xor(suma1, 16, 64);
    suma1 += __shfl_xor(suma1, 32, 64);

    // ---- epilogue: shared v1/v2 loads serve both q's; At/As as float4 ----
    const int d = tid & 63;
    const int g = tid >> 6;               // 0..7, each covers 24 rows
    const float* v1p = v1g + hb;
    const float* v2p = v2g + hb;
    float zp0 = 0.f, zp1 = 0.f;
    #pragma unroll 1
    for (int rb = 0; rb < 24; rb += 4) {
        int t0 = g * 24 + rb;
        float4 at0 = *(const float4*)&AT(0, t0);
        float4 as0 = *(const float4*)&AS(0, t0);
        float4 at1 = *(const float4*)&AT(1, t0);
        float4 as1 = *(const float4*)&AS(1, t0);
        #pragma unroll
        for (int r2 = 0; r2 < 4; ++r2) {
            int t = t0 + r2;
            float x1 = v1p[t * DD + d];
            float x2 = v2p[t * DD + d];
            float a0 = (r2 == 0) ? at0.x : (r2 == 1) ? at0.y : (r2 == 2) ? at0.z : at0.w;
            float s0 = (r2 == 0) ? as0.x : (r2 == 1) ? as0.y : (r2 == 2) ? as0.z : as0.w;
            float a1 = (r2 == 0) ? at1.x : (r2 == 1) ? at1.y : (r2 == 2) ? at1.z : at1.w;
            float s1 = (r2 == 0) ? as1.x : (r2 == 1) ? as1.y : (r2 == 2) ? as1.z : as1.w;
            zp0 = fmaf(a0, x1, fmaf(s0, x2, zp0));
            zp1 = fmaf(a1, x1, fmaf(s1, x2, zp1));
        }
    }
    atomicAdd(&ZSH(0, d), zp0);
    atomicAdd(&ZSH(1, d), zp1);
    __syncthreads();

    if (tid < DD) {
        zg[(size_t)q0 * DD + tid] = ZSH(0, tid) / suma0;
    } else if (tid < 2 * DD) {
        zg[(size_t)(q0 + 1) * DD + (tid - DD)] = ZSH(1, tid - DD) / suma1;
    }
    if (tid == 0) lseg[q0] = logf(suma0);
    if (tid == 1) lseg[q0 + 1] = logf(suma1);
}

extern "C" void kernel_launch(void* const* d_in, const int* in_sizes, int n_in,
                              void* d_out, int out_size, void* d_ws, size_t ws_size,
                              hipStream_t stream) {
    const float* q  = (const float*)d_in[0];
    const float* k1 = (const float*)d_in[1];
    const float* k2 = (const float*)d_in[2];
    const float* v1 = (const float*)d_in[3];
    const float* v2 = (const float*)d_in[4];
    float* out = (float*)d_out;

    const int nq = in_sizes[0] / DD;      // B*H*S = 3072
    const int nheads = nq / SS;           // 16
    float* zout   = out;
    float* lseout = out + (size_t)nq * DD;
    uint4* k2pack = (uint4*)d_ws;         // nheads*192*64 bf16 = 384 KiB

    // prepack k2 -> bf16 pre-swizzled (q-invariant; deterministic each call)
    int n8 = nheads * SS * DD / 8;        // 24576
    hipLaunchKernelGGL(k2_pack, dim3(n8 / 512), dim3(512), 0, stream, k2, k2pack);

    dim3 grid(nq / 2), block(NT);
    hipLaunchKernelGGL(tritt_fwd, grid, block, 0, stream,
                       q, k1, (const uint4*)k2pack, v1, v2, zout, lseout);
}